// Round 1
// 279.419 us; speedup vs baseline: 1.0080x; 1.0080x over previous
//
#include <hip/hip_runtime.h>
#include <hip/hip_bf16.h>
#include <math.h>

#define Bn 8
#define Tn 2048
#define Cn 1024
#define Hn 64
#define BTHb ((size_t)Bn * Tn * Hn)   // elements per projected matrix (bf16)

typedef __attribute__((ext_vector_type(8))) short bf16x8;
typedef __attribute__((ext_vector_type(4))) float f32x4;

static __device__ __forceinline__ unsigned short bf16rne(float f) {
    union { float f; unsigned u; } x; x.f = f;
    return (unsigned short)((x.u + 0x7FFFu + ((x.u >> 16) & 1u)) >> 16);
}

// ---------------------------------------------------------------------------
// MFMA projection -> bf16 output: O[row,h] = sum_c X[row,c] * W[h,c]
// grid (256, 3); block 256 = 4 waves; 64 rows x 64 h per block.
// v2: 2-deep register prefetch + double-buffered LDS, ONE barrier per
// 64-col chunk (was 2). Loads for chunk c+2 are issued at the top of
// chunk c, so their vmcnt wait (at the conversion in chunk c+1) is a full
// chunk-phase after issue -> deep, continuous in-flight queue instead of
// the per-chunk vmcnt(0) drain that capped HBM at ~1.3 TB/s.
// ---------------------------------------------------------------------------
__global__ __launch_bounds__(256) void proj_kernel(
    const float* __restrict__ k, const float* __restrict__ q,
    const float* __restrict__ v,
    const float* __restrict__ Wk, const float* __restrict__ Wq,
    const float* __restrict__ Wv,
    unsigned short* __restrict__ ws)
{
    const int which = blockIdx.y;
    const float* X = (which == 0) ? k : (which == 1) ? q : v;
    const float* W = (which == 0) ? Wk : (which == 1) ? Wq : Wv;
    unsigned short* O = ws + (size_t)which * BTHb;

    __shared__ unsigned short Xs[2][64][72];
    __shared__ unsigned short Wt[2][64][72];

    const int tid  = threadIdx.x;
    const int wave = __builtin_amdgcn_readfirstlane(tid >> 6);
    const int lane = tid & 63;
    const int m    = lane & 15;
    const int quad = lane >> 4;
    const int row0 = blockIdx.x * 64;

    const int srow = tid >> 4;          // 0..15: thread covers rows srow+16u
    const int sc4  = tid & 15;          // float4 index within 64-col chunk

    const float* Xb = X + (size_t)(row0 + srow) * Cn + sc4 * 4;
    const float* Wb = W + (size_t)srow * Cn + sc4 * 4;

    f32x4 acc[4];
#pragma unroll
    for (int t = 0; t < 4; ++t) acc[t] = (f32x4){0.f, 0.f, 0.f, 0.f};

    float4 xr0[4], wr0[4], xr1[4], wr1[4];

#define LOADSET(xr, wr, c)                                                   \
    do {                                                                     \
        _Pragma("unroll")                                                    \
        for (int u = 0; u < 4; ++u) {                                        \
            xr[u] = *(const float4*)(Xb + (size_t)(16 * u) * Cn + (c) * 64); \
            wr[u] = *(const float4*)(Wb + (size_t)(16 * u) * Cn + (c) * 64); \
        }                                                                    \
    } while (0)

#define CONVSET(xr, wr, buf)                                                 \
    do {                                                                     \
        _Pragma("unroll")                                                    \
        for (int u = 0; u < 4; ++u) {                                        \
            const int row = srow + 16 * u;                                   \
            ushort4 xb, wb;                                                  \
            xb.x = bf16rne(xr[u].x); xb.y = bf16rne(xr[u].y);                \
            xb.z = bf16rne(xr[u].z); xb.w = bf16rne(xr[u].w);                \
            wb.x = bf16rne(wr[u].x); wb.y = bf16rne(wr[u].y);                \
            wb.z = bf16rne(wr[u].z); wb.w = bf16rne(wr[u].w);                \
            *(ushort4*)&Xs[buf][row][sc4 * 4] = xb;                          \
            *(ushort4*)&Wt[buf][row][sc4 * 4] = wb;                          \
        }                                                                    \
    } while (0)

#define MFMAS(buf)                                                           \
    do {                                                                     \
        _Pragma("unroll")                                                    \
        for (int kc = 0; kc < 64; kc += 32) {                                \
            const bf16x8 a =                                                 \
                *(const bf16x8*)&Xs[buf][wave * 16 + m][kc + quad * 8];      \
            _Pragma("unroll")                                                \
            for (int ht = 0; ht < 4; ++ht) {                                 \
                const bf16x8 bfr =                                           \
                    *(const bf16x8*)&Wt[buf][ht * 16 + m][kc + quad * 8];    \
                acc[ht] = __builtin_amdgcn_mfma_f32_16x16x32_bf16(           \
                    a, bfr, acc[ht], 0, 0, 0);                               \
            }                                                                \
        }                                                                    \
    } while (0)

    // prologue: chunk0 -> set0 -> LDS[0]; chunk1 -> set1 (in flight)
    LOADSET(xr0, wr0, 0);
    LOADSET(xr1, wr1, 1);
    CONVSET(xr0, wr0, 0);
    __syncthreads();

    for (int c2 = 0; c2 < 8; ++c2) {
        const int ct = c2 * 2;
        // even iter: compute LDS[0] (chunk ct), stage chunk ct+1 -> LDS[1]
        if (ct + 2 < 16) LOADSET(xr0, wr0, ct + 2);
        CONVSET(xr1, wr1, 1);
        MFMAS(0);
        __syncthreads();
        // odd iter: compute LDS[1] (chunk ct+1), stage chunk ct+2 -> LDS[0]
        if (ct + 3 < 16) LOADSET(xr1, wr1, ct + 3);
        if (ct + 2 < 16) CONVSET(xr0, wr0, 0);
        MFMAS(1);
        __syncthreads();
    }

#undef LOADSET
#undef CONVSET
#undef MFMAS

    // D layout: col=lane&15, row=quad*4+reg
#pragma unroll
    for (int ht = 0; ht < 4; ++ht)
#pragma unroll
        for (int r = 0; r < 4; ++r)
            O[(size_t)(row0 + wave * 16 + quad * 4 + r) * Hn + ht * 16 + m] =
                bf16rne(acc[ht][r]);
}

// ---------------------------------------------------------------------------
// MFMA flash attention. grid (32, 8); block 256 = 4 waves.
// Block bx = q-tile of 64 rows (qt*64..+64); wave w owns rows wrb..wrb+16.
// k-loop j = 0..qt over 64-key tiles: stage K (row-major) + V^T (dim-major)
// bf16 in LDS, QK^T via 16x16x32 MFMA (4 col-tiles x 2 k-chunks), online
// softmax in C-layout registers, P -> LDS (bf16) -> A-frag, PV via MFMA.
// ---------------------------------------------------------------------------
__global__ __launch_bounds__(256) void attn_kernel(
    const unsigned short* __restrict__ ws,
    const int* __restrict__ mask,
    float* __restrict__ out)
{
    const unsigned short* kh = ws;
    const unsigned short* qh = ws + BTHb;
    const unsigned short* vh = ws + 2 * BTHb;

    const int b   = blockIdx.y;
    const int qt  = blockIdx.x;
    const int tid = threadIdx.x;
    const int wave = __builtin_amdgcn_readfirstlane(tid >> 6);
    const int lane = tid & 63;
    const int ln   = lane & 15;
    const int quad = lane >> 4;

    __shared__ unsigned short Ks[64][72];   // [kpos][dim]
    __shared__ unsigned short Vt[64][72];   // [dim][kpos]
    __shared__ unsigned short Ps[64][72];   // [q-row local][kpos]
    __shared__ int Msk[64];

    const int wrb = qt * 64 + wave * 16;    // wave's first q-row

    // Q A-frags: A[m=ln][k=quad*8+j], 2 chunks of K=32
    bf16x8 qa[2];
#pragma unroll
    for (int kc = 0; kc < 2; ++kc)
        qa[kc] = *(const bf16x8*)(qh + ((size_t)b * Tn + wrb + ln) * Hn
                                     + kc * 32 + quad * 8);

    f32x4 oacc[4];
#pragma unroll
    for (int t = 0; t < 4; ++t) oacc[t] = (f32x4){0.f, 0.f, 0.f, 0.f};
    float mrow[4] = {-1e30f, -1e30f, -1e30f, -1e30f};
    float lrow[4] = {0.f, 0.f, 0.f, 0.f};

    // staging: K by (row=tid>>2, seg=tid&3)  [coalesced global, b128 LDS]
    //          V by (col=tid&63, seg=tid>>6) [conflict-free transpose writes]
    const int krow = tid >> 2, kseg = tid & 3;
    const int vcol = tid & 63, vseg = tid >> 6;

    uint4 kreg[2], vreg[2];
    int mreg = 0;
    {
        const unsigned short* kp =
            kh + ((size_t)b * Tn + krow) * Hn + kseg * 16;
        kreg[0] = *(const uint4*)kp;
        kreg[1] = *(const uint4*)(kp + 8);
        const unsigned short* vp =
            vh + ((size_t)b * Tn + vcol) * Hn + vseg * 16;
        vreg[0] = *(const uint4*)vp;
        vreg[1] = *(const uint4*)(vp + 8);
        if (tid < 64) mreg = mask[(size_t)b * Tn + tid];
    }

    for (int j = 0; j <= qt; ++j) {
        __syncthreads();   // previous tile's LDS readers done
        *(uint4*)&Ks[krow][kseg * 16]     = kreg[0];
        *(uint4*)&Ks[krow][kseg * 16 + 8] = kreg[1];
        {
            const unsigned short* vs = (const unsigned short*)vreg;
#pragma unroll
            for (int jj = 0; jj < 16; ++jj)
                Vt[vseg * 16 + jj][vcol] = vs[jj];
        }
        if (tid < 64) Msk[tid] = mreg;
        __syncthreads();   // staged tile visible

        if (j < qt) {      // prefetch next tile; latency overlaps compute
            const unsigned short* kp =
                kh + ((size_t)b * Tn + (j + 1) * 64 + krow) * Hn + kseg * 16;
            kreg[0] = *(const uint4*)kp;
            kreg[1] = *(const uint4*)(kp + 8);
            const unsigned short* vp =
                vh + ((size_t)b * Tn + (j + 1) * 64 + vcol) * Hn + vseg * 16;
            vreg[0] = *(const uint4*)vp;
            vreg[1] = *(const uint4*)(vp + 8);
            if (tid < 64) mreg = mask[(size_t)b * Tn + (j + 1) * 64 + tid];
        }

        // ---- S = Q K^T : 4 col-tiles (16 kpos each) x 2 K-chunks ----
        f32x4 sacc[4];
#pragma unroll
        for (int t = 0; t < 4; ++t) sacc[t] = (f32x4){0.f, 0.f, 0.f, 0.f};
#pragma unroll
        for (int kc = 0; kc < 2; ++kc) {
#pragma unroll
            for (int nt = 0; nt < 4; ++nt) {
                const bf16x8 kb =
                    *(const bf16x8*)&Ks[nt * 16 + ln][kc * 32 + quad * 8];
                sacc[nt] = __builtin_amdgcn_mfma_f32_16x16x32_bf16(
                    qa[kc], kb, sacc[nt], 0, 0, 0);
            }
        }

        // ---- online softmax in C-layout (rows quad*4+r, col nt*16+ln) ----
        const bool fullv = (j < qt);   // tile fully causal-valid for block
        float pv[4][4];
        float mt[4] = {-1e30f, -1e30f, -1e30f, -1e30f};
#pragma unroll
        for (int nt = 0; nt < 4; ++nt) {
            const bool mk = (Msk[nt * 16 + ln] != 0);
            const int kpos = j * 64 + nt * 16 + ln;
#pragma unroll
            for (int r = 0; r < 4; ++r) {
                float s = sacc[nt][r] * 0.125f;
                const bool valid =
                    mk && (fullv || kpos <= wrb + quad * 4 + r);
                s = valid ? s : -1e30f;
                pv[nt][r] = s;
                mt[r] = fmaxf(mt[r], s);
            }
        }
#pragma unroll
        for (int r = 0; r < 4; ++r) {
            mt[r] = fmaxf(mt[r], __shfl_xor(mt[r], 1));
            mt[r] = fmaxf(mt[r], __shfl_xor(mt[r], 2));
            mt[r] = fmaxf(mt[r], __shfl_xor(mt[r], 4));
            mt[r] = fmaxf(mt[r], __shfl_xor(mt[r], 8));
        }
        float alpha[4], rsum[4];
#pragma unroll
        for (int r = 0; r < 4; ++r) {
            const float mn = fmaxf(mrow[r], mt[r]);
            alpha[r] = __expf(mrow[r] - mn);
            mrow[r] = mn;
            rsum[r] = 0.f;
        }
#pragma unroll
        for (int nt = 0; nt < 4; ++nt)
#pragma unroll
            for (int r = 0; r < 4; ++r) {
                const float p = (pv[nt][r] <= -1e29f)
                                    ? 0.f
                                    : __expf(pv[nt][r] - mrow[r]);
                pv[nt][r] = p;
                rsum[r] += p;
            }
#pragma unroll
        for (int r = 0; r < 4; ++r) {
            rsum[r] += __shfl_xor(rsum[r], 1);
            rsum[r] += __shfl_xor(rsum[r], 2);
            rsum[r] += __shfl_xor(rsum[r], 4);
            rsum[r] += __shfl_xor(rsum[r], 8);
            lrow[r] = lrow[r] * alpha[r] + rsum[r];
        }
#pragma unroll
        for (int nt = 0; nt < 4; ++nt)
#pragma unroll
            for (int r = 0; r < 4; ++r) oacc[nt][r] *= alpha[r];

        // ---- P -> LDS (bf16), wave-private region ----
#pragma unroll
        for (int nt = 0; nt < 4; ++nt)
#pragma unroll
            for (int r = 0; r < 4; ++r)
                Ps[wave * 16 + quad * 4 + r][nt * 16 + ln] =
                    bf16rne(pv[nt][r]);
        // wave-private LDS round-trip: drain DS writes, keep vmcnt in flight
        asm volatile("s_waitcnt lgkmcnt(0)" ::: "memory");

        // ---- O += P V : A=P[m=ln][k], B=V^T[n=dim][k] ----
#pragma unroll
        for (int kc = 0; kc < 2; ++kc) {
            const bf16x8 pa =
                *(const bf16x8*)&Ps[wave * 16 + ln][kc * 32 + quad * 8];
#pragma unroll
            for (int nt = 0; nt < 4; ++nt) {
                const bf16x8 vb =
                    *(const bf16x8*)&Vt[nt * 16 + ln][kc * 32 + quad * 8];
                oacc[nt] = __builtin_amdgcn_mfma_f32_16x16x32_bf16(
                    pa, vb, oacc[nt], 0, 0, 0);
            }
        }
    }

    // ---- epilogue: divide by l, fp32 store ----
#pragma unroll
    for (int r = 0; r < 4; ++r) {
        const float inv = 1.0f / lrow[r];
        const size_t rowoff = ((size_t)b * Tn + wrb + quad * 4 + r) * Hn;
#pragma unroll
        for (int nt = 0; nt < 4; ++nt)
            out[rowoff + nt * 16 + ln] = oacc[nt][r] * inv;
    }
}

extern "C" void kernel_launch(void* const* d_in, const int* in_sizes, int n_in,
                              void* d_out, int out_size, void* d_ws, size_t ws_size,
                              hipStream_t stream)
{
    const float* k    = (const float*)d_in[0];
    const float* q    = (const float*)d_in[1];
    const float* v    = (const float*)d_in[2];
    const int*   mask = (const int*)d_in[3];
    const float* Wk   = (const float*)d_in[4];
    const float* Wq   = (const float*)d_in[5];
    const float* Wv   = (const float*)d_in[6];
    float* out = (float*)d_out;
    unsigned short* ws = (unsigned short*)d_ws;  // kh|qh|vh bf16, 6.3 MB

    dim3 pb(256), pg(Bn * Tn / 64, 3);
    proj_kernel<<<pg, pb, 0, stream>>>(k, q, v, Wk, Wq, Wv, ws);

    dim3 ab(256), ag(Tn / 64, Bn);
    attn_kernel<<<ag, ab, 0, stream>>>(ws, mask, out);
}

// Round 2
// 277.880 us; speedup vs baseline: 1.0136x; 1.0055x over previous
//
#include <hip/hip_runtime.h>
#include <hip/hip_bf16.h>
#include <math.h>

#define Bn 8
#define Tn 2048
#define Cn 1024
#define Hn 64
#define BTHb ((size_t)Bn * Tn * Hn)   // elements per projected matrix (bf16)

typedef __attribute__((ext_vector_type(8))) short bf16x8;
typedef __attribute__((ext_vector_type(4))) float f32x4;

static __device__ __forceinline__ unsigned short bf16rne(float f) {
    union { float f; unsigned u; } x; x.f = f;
    return (unsigned short)((x.u + 0x7FFFu + ((x.u >> 16) & 1u)) >> 16);
}

// ---------------------------------------------------------------------------
// MFMA projection -> bf16 output: O[row,h] = sum_c X[row,c] * W[h,c]
// grid (256, 3); block 256 = 4 waves; 64 rows x 64 h per block.
// v3: depth-4 register prefetch (sets indexed chunk%4, fully unrolled so
// every index is compile-time) + LDS double buffer, ONE barrier per chunk.
// __launch_bounds__(256,3) sets amdgpu-waves-per-eu=3 so the allocator may
// use ~170 VGPRs: v2 failed because the default occupancy heuristic chose
// 52 VGPRs, which cannot hold even two 32-reg prefetch sets -> loads were
// serialized (vmcnt drain per load) -> 1.3 TB/s. Grid gives only 3
// blocks/CU, so the register budget costs no occupancy.
// ---------------------------------------------------------------------------
__global__ __launch_bounds__(256, 3) void proj_kernel(
    const float* __restrict__ k, const float* __restrict__ q,
    const float* __restrict__ v,
    const float* __restrict__ Wk, const float* __restrict__ Wq,
    const float* __restrict__ Wv,
    unsigned short* __restrict__ ws)
{
    const int which = blockIdx.y;
    const float* X = (which == 0) ? k : (which == 1) ? q : v;
    const float* W = (which == 0) ? Wk : (which == 1) ? Wq : Wv;
    unsigned short* O = ws + (size_t)which * BTHb;

    __shared__ unsigned short Xs[2][64][72];
    __shared__ unsigned short Wt[2][64][72];

    const int tid  = threadIdx.x;
    const int wave = __builtin_amdgcn_readfirstlane(tid >> 6);
    const int lane = tid & 63;
    const int m    = lane & 15;
    const int quad = lane >> 4;
    const int row0 = blockIdx.x * 64;

    const int srow = tid >> 4;          // 0..15: thread covers rows srow+16u
    const int sc4  = tid & 15;          // float4 index within 64-col chunk

    const float* Xb = X + (size_t)(row0 + srow) * Cn + sc4 * 4;
    const float* Wb = W + (size_t)srow * Cn + sc4 * 4;

    f32x4 acc[4];
#pragma unroll
    for (int t = 0; t < 4; ++t) acc[t] = (f32x4){0.f, 0.f, 0.f, 0.f};

    // 4 prefetch sets: set s holds chunk c with c%4 == s. 128 VGPRs.
    float4 xr[4][4], wr[4][4];

#define LOADSET(s, c)                                                        \
    do {                                                                     \
        _Pragma("unroll")                                                    \
        for (int u = 0; u < 4; ++u) {                                        \
            xr[s][u] =                                                       \
                *(const float4*)(Xb + (size_t)(16 * u) * Cn + (c) * 64);     \
            wr[s][u] =                                                       \
                *(const float4*)(Wb + (size_t)(16 * u) * Cn + (c) * 64);     \
        }                                                                    \
    } while (0)

#define CONVSET(s, buf)                                                      \
    do {                                                                     \
        _Pragma("unroll")                                                    \
        for (int u = 0; u < 4; ++u) {                                        \
            const int row = srow + 16 * u;                                   \
            ushort4 xb, wb;                                                  \
            xb.x = bf16rne(xr[s][u].x); xb.y = bf16rne(xr[s][u].y);          \
            xb.z = bf16rne(xr[s][u].z); xb.w = bf16rne(xr[s][u].w);          \
            wb.x = bf16rne(wr[s][u].x); wb.y = bf16rne(wr[s][u].y);          \
            wb.z = bf16rne(wr[s][u].z); wb.w = bf16rne(wr[s][u].w);          \
            *(ushort4*)&Xs[buf][row][sc4 * 4] = xb;                          \
            *(ushort4*)&Wt[buf][row][sc4 * 4] = wb;                          \
        }                                                                    \
    } while (0)

#define MFMAS(buf)                                                           \
    do {                                                                     \
        _Pragma("unroll")                                                    \
        for (int kc = 0; kc < 64; kc += 32) {                                \
            const bf16x8 a =                                                 \
                *(const bf16x8*)&Xs[buf][wave * 16 + m][kc + quad * 8];      \
            _Pragma("unroll")                                                \
            for (int ht = 0; ht < 4; ++ht) {                                 \
                const bf16x8 bfr =                                           \
                    *(const bf16x8*)&Wt[buf][ht * 16 + m][kc + quad * 8];    \
                acc[ht] = __builtin_amdgcn_mfma_f32_16x16x32_bf16(           \
                    a, bfr, acc[ht], 0, 0, 0);                               \
            }                                                                \
        }                                                                    \
    } while (0)

    // prologue: chunks 0..3 in flight; chunk 0 converted into LDS[0]
    LOADSET(0, 0);
    LOADSET(1, 1);
    LOADSET(2, 2);
    LOADSET(3, 3);
    CONVSET(0, 0);
    __syncthreads();

    // phase c: refill set c%4 with chunk c+4, convert chunk c+1 into
    // LDS[(c+1)&1], run MFMAs on LDS[c&1] (chunk c), one barrier.
#pragma unroll
    for (int c = 0; c < 16; ++c) {
        if (c + 4 < 16) LOADSET(c & 3, c + 4);
        if (c + 1 < 16) CONVSET((c + 1) & 3, (c + 1) & 1);
        MFMAS(c & 1);
        if (c + 1 < 16) __syncthreads();
    }

#undef LOADSET
#undef CONVSET
#undef MFMAS

    // D layout: col=lane&15, row=quad*4+reg
#pragma unroll
    for (int ht = 0; ht < 4; ++ht)
#pragma unroll
        for (int r = 0; r < 4; ++r)
            O[(size_t)(row0 + wave * 16 + quad * 4 + r) * Hn + ht * 16 + m] =
                bf16rne(acc[ht][r]);
}

// ---------------------------------------------------------------------------
// MFMA flash attention. grid (32, 8); block 256 = 4 waves.
// Block bx = q-tile of 64 rows (qt*64..+64); wave w owns rows wrb..wrb+16.
// k-loop j = 0..qt over 64-key tiles: stage K (row-major) + V^T (dim-major)
// bf16 in LDS, QK^T via 16x16x32 MFMA (4 col-tiles x 2 k-chunks), online
// softmax in C-layout registers, P -> LDS (bf16) -> A-frag, PV via MFMA.
// ---------------------------------------------------------------------------
__global__ __launch_bounds__(256) void attn_kernel(
    const unsigned short* __restrict__ ws,
    const int* __restrict__ mask,
    float* __restrict__ out)
{
    const unsigned short* kh = ws;
    const unsigned short* qh = ws + BTHb;
    const unsigned short* vh = ws + 2 * BTHb;

    const int b   = blockIdx.y;
    const int qt  = blockIdx.x;
    const int tid = threadIdx.x;
    const int wave = __builtin_amdgcn_readfirstlane(tid >> 6);
    const int lane = tid & 63;
    const int ln   = lane & 15;
    const int quad = lane >> 4;

    __shared__ unsigned short Ks[64][72];   // [kpos][dim]
    __shared__ unsigned short Vt[64][72];   // [dim][kpos]
    __shared__ unsigned short Ps[64][72];   // [q-row local][kpos]
    __shared__ int Msk[64];

    const int wrb = qt * 64 + wave * 16;    // wave's first q-row

    // Q A-frags: A[m=ln][k=quad*8+j], 2 chunks of K=32
    bf16x8 qa[2];
#pragma unroll
    for (int kc = 0; kc < 2; ++kc)
        qa[kc] = *(const bf16x8*)(qh + ((size_t)b * Tn + wrb + ln) * Hn
                                     + kc * 32 + quad * 8);

    f32x4 oacc[4];
#pragma unroll
    for (int t = 0; t < 4; ++t) oacc[t] = (f32x4){0.f, 0.f, 0.f, 0.f};
    float mrow[4] = {-1e30f, -1e30f, -1e30f, -1e30f};
    float lrow[4] = {0.f, 0.f, 0.f, 0.f};

    // staging: K by (row=tid>>2, seg=tid&3)  [coalesced global, b128 LDS]
    //          V by (col=tid&63, seg=tid>>6) [conflict-free transpose writes]
    const int krow = tid >> 2, kseg = tid & 3;
    const int vcol = tid & 63, vseg = tid >> 6;

    uint4 kreg[2], vreg[2];
    int mreg = 0;
    {
        const unsigned short* kp =
            kh + ((size_t)b * Tn + krow) * Hn + kseg * 16;
        kreg[0] = *(const uint4*)kp;
        kreg[1] = *(const uint4*)(kp + 8);
        const unsigned short* vp =
            vh + ((size_t)b * Tn + vcol) * Hn + vseg * 16;
        vreg[0] = *(const uint4*)vp;
        vreg[1] = *(const uint4*)(vp + 8);
        if (tid < 64) mreg = mask[(size_t)b * Tn + tid];
    }

    for (int j = 0; j <= qt; ++j) {
        __syncthreads();   // previous tile's LDS readers done
        *(uint4*)&Ks[krow][kseg * 16]     = kreg[0];
        *(uint4*)&Ks[krow][kseg * 16 + 8] = kreg[1];
        {
            const unsigned short* vs = (const unsigned short*)vreg;
#pragma unroll
            for (int jj = 0; jj < 16; ++jj)
                Vt[vseg * 16 + jj][vcol] = vs[jj];
        }
        if (tid < 64) Msk[tid] = mreg;
        __syncthreads();   // staged tile visible

        if (j < qt) {      // prefetch next tile; latency overlaps compute
            const unsigned short* kp =
                kh + ((size_t)b * Tn + (j + 1) * 64 + krow) * Hn + kseg * 16;
            kreg[0] = *(const uint4*)kp;
            kreg[1] = *(const uint4*)(kp + 8);
            const unsigned short* vp =
                vh + ((size_t)b * Tn + (j + 1) * 64 + vcol) * Hn + vseg * 16;
            vreg[0] = *(const uint4*)vp;
            vreg[1] = *(const uint4*)(vp + 8);
            if (tid < 64) mreg = mask[(size_t)b * Tn + (j + 1) * 64 + tid];
        }

        // ---- S = Q K^T : 4 col-tiles (16 kpos each) x 2 K-chunks ----
        f32x4 sacc[4];
#pragma unroll
        for (int t = 0; t < 4; ++t) sacc[t] = (f32x4){0.f, 0.f, 0.f, 0.f};
#pragma unroll
        for (int kc = 0; kc < 2; ++kc) {
#pragma unroll
            for (int nt = 0; nt < 4; ++nt) {
                const bf16x8 kb =
                    *(const bf16x8*)&Ks[nt * 16 + ln][kc * 32 + quad * 8];
                sacc[nt] = __builtin_amdgcn_mfma_f32_16x16x32_bf16(
                    qa[kc], kb, sacc[nt], 0, 0, 0);
            }
        }

        // ---- online softmax in C-layout (rows quad*4+r, col nt*16+ln) ----
        const bool fullv = (j < qt);   // tile fully causal-valid for block
        float pv[4][4];
        float mt[4] = {-1e30f, -1e30f, -1e30f, -1e30f};
#pragma unroll
        for (int nt = 0; nt < 4; ++nt) {
            const bool mk = (Msk[nt * 16 + ln] != 0);
            const int kpos = j * 64 + nt * 16 + ln;
#pragma unroll
            for (int r = 0; r < 4; ++r) {
                float s = sacc[nt][r] * 0.125f;
                const bool valid =
                    mk && (fullv || kpos <= wrb + quad * 4 + r);
                s = valid ? s : -1e30f;
                pv[nt][r] = s;
                mt[r] = fmaxf(mt[r], s);
            }
        }
#pragma unroll
        for (int r = 0; r < 4; ++r) {
            mt[r] = fmaxf(mt[r], __shfl_xor(mt[r], 1));
            mt[r] = fmaxf(mt[r], __shfl_xor(mt[r], 2));
            mt[r] = fmaxf(mt[r], __shfl_xor(mt[r], 4));
            mt[r] = fmaxf(mt[r], __shfl_xor(mt[r], 8));
        }
        float alpha[4], rsum[4];
#pragma unroll
        for (int r = 0; r < 4; ++r) {
            const float mn = fmaxf(mrow[r], mt[r]);
            alpha[r] = __expf(mrow[r] - mn);
            mrow[r] = mn;
            rsum[r] = 0.f;
        }
#pragma unroll
        for (int nt = 0; nt < 4; ++nt)
#pragma unroll
            for (int r = 0; r < 4; ++r) {
                const float p = (pv[nt][r] <= -1e29f)
                                    ? 0.f
                                    : __expf(pv[nt][r] - mrow[r]);
                pv[nt][r] = p;
                rsum[r] += p;
            }
#pragma unroll
        for (int r = 0; r < 4; ++r) {
            rsum[r] += __shfl_xor(rsum[r], 1);
            rsum[r] += __shfl_xor(rsum[r], 2);
            rsum[r] += __shfl_xor(rsum[r], 4);
            rsum[r] += __shfl_xor(rsum[r], 8);
            lrow[r] = lrow[r] * alpha[r] + rsum[r];
        }
#pragma unroll
        for (int nt = 0; nt < 4; ++nt)
#pragma unroll
            for (int r = 0; r < 4; ++r) oacc[nt][r] *= alpha[r];

        // ---- P -> LDS (bf16), wave-private region ----
#pragma unroll
        for (int nt = 0; nt < 4; ++nt)
#pragma unroll
            for (int r = 0; r < 4; ++r)
                Ps[wave * 16 + quad * 4 + r][nt * 16 + ln] =
                    bf16rne(pv[nt][r]);
        // wave-private LDS round-trip: drain DS writes, keep vmcnt in flight
        asm volatile("s_waitcnt lgkmcnt(0)" ::: "memory");

        // ---- O += P V : A=P[m=ln][k], B=V^T[n=dim][k] ----
#pragma unroll
        for (int kc = 0; kc < 2; ++kc) {
            const bf16x8 pa =
                *(const bf16x8*)&Ps[wave * 16 + ln][kc * 32 + quad * 8];
#pragma unroll
            for (int nt = 0; nt < 4; ++nt) {
                const bf16x8 vb =
                    *(const bf16x8*)&Vt[nt * 16 + ln][kc * 32 + quad * 8];
                oacc[nt] = __builtin_amdgcn_mfma_f32_16x16x32_bf16(
                    pa, vb, oacc[nt], 0, 0, 0);
            }
        }
    }

    // ---- epilogue: divide by l, fp32 store ----
#pragma unroll
    for (int r = 0; r < 4; ++r) {
        const float inv = 1.0f / lrow[r];
        const size_t rowoff = ((size_t)b * Tn + wrb + quad * 4 + r) * Hn;
#pragma unroll
        for (int nt = 0; nt < 4; ++nt)
            out[rowoff + nt * 16 + ln] = oacc[nt][r] * inv;
    }
}

extern "C" void kernel_launch(void* const* d_in, const int* in_sizes, int n_in,
                              void* d_out, int out_size, void* d_ws, size_t ws_size,
                              hipStream_t stream)
{
    const float* k    = (const float*)d_in[0];
    const float* q    = (const float*)d_in[1];
    const float* v    = (const float*)d_in[2];
    const int*   mask = (const int*)d_in[3];
    const float* Wk   = (const float*)d_in[4];
    const float* Wq   = (const float*)d_in[5];
    const float* Wv   = (const float*)d_in[6];
    float* out = (float*)d_out;
    unsigned short* ws = (unsigned short*)d_ws;  // kh|qh|vh bf16, 6.3 MB

    dim3 pb(256), pg(Bn * Tn / 64, 3);
    proj_kernel<<<pg, pb, 0, stream>>>(k, q, v, Wk, Wq, Wv, ws);

    dim3 ab(256), ag(Tn / 64, Bn);
    attn_kernel<<<ag, ab, 0, stream>>>(ws, mask, out);
}